// Round 9
// baseline (95.833 us; speedup 1.0000x reference)
//
#include <hip/hip_runtime.h>
#include <stdint.h>

#define BATCH 8192
#define DIM 256
#define NSPLIT 16
#define BM 256
#define BN 64
#define COLS_PER_SPLIT (BATCH / NSPLIT)   // 512
#define NTILES (COLS_PER_SPLIT / BN)      // 8
#define LOG2E 1.4426950408889634f
#define LN2   0.6931471805599453f

typedef float floatx4 __attribute__((ext_vector_type(4)));
typedef float floatx2 __attribute__((ext_vector_type(2)));
typedef int intx4 __attribute__((ext_vector_type(4)));
typedef int intx8 __attribute__((ext_vector_type(8)));

union frag8 { intx8 v8; intx4 v4[2]; };

__device__ __forceinline__ float fast_exp2(float x) {
#if __has_builtin(__builtin_amdgcn_exp2f)
    return __builtin_amdgcn_exp2f(x);
#else
    return exp2f(x);
#endif
}

// ---------------------------------------------------------------------------
// Prep: fp32 -> fp8 e4m3 (HW cvt_pk) into f8f6f4 fragment layout.
// Per 16-row tile (4 KB): byte = tile*4096 + kstep*2048 + half*1024
//                                + (kgroup*16+row)*16 + (k&15).
// Also t2[j], diag[i] (fp32, exact), t2c2[j] = t2[j] * (-0.5*LOG2E/sg^2),
// and zeroes the finish-stage atomic counter (workspace is re-poisoned
// every iteration, so the counter must be re-armed here; stream order
// guarantees prep completes before finish1 starts).
// ---------------------------------------------------------------------------
__global__ __launch_bounds__(256) void prep_kernel(
        const float* __restrict__ pred, const float* __restrict__ target,
        const float* __restrict__ sigma,
        uint8_t* __restrict__ Ap, uint8_t* __restrict__ Bp,
        float* __restrict__ t2, float* __restrict__ diag,
        float* __restrict__ t2c2, unsigned* __restrict__ cnt) {
    __shared__ __align__(16) uint8_t ldsA[4096];
    __shared__ __align__(16) uint8_t ldsB[4096];
    const int t = threadIdx.x;
    const int r = t >> 4, c = t & 15;
    const int rt = blockIdx.x;
    const int row = rt * 16 + r;

    if (rt == 0 && t == 0) *cnt = 0u;

    float dsum = 0.f, tsum = 0.f;
#pragma unroll
    for (int q = 0; q < 4; ++q) {
        const int k0 = q * 64 + c * 4;
        const float4 p4 = *(const float4*)(pred + (size_t)row * DIM + k0);
        const float4 t4 = *(const float4*)(target + (size_t)row * DIM + k0);
        dsum += p4.x * t4.x + p4.y * t4.y + p4.z * t4.z + p4.w * t4.w;
        tsum += t4.x * t4.x + t4.y * t4.y + t4.z * t4.z + t4.w * t4.w;
        const int kstep  = k0 >> 7;
        const int kgroup = (k0 >> 5) & 3;
        const int half   = (k0 >> 4) & 1;
        const int b      = k0 & 15;
        const int off = kstep * 2048 + half * 1024 + (kgroup * 16 + r) * 16 + b;
        int pp = __builtin_amdgcn_cvt_pk_fp8_f32(p4.x, p4.y, 0, false);
        pp     = __builtin_amdgcn_cvt_pk_fp8_f32(p4.z, p4.w, pp, true);
        int tt = __builtin_amdgcn_cvt_pk_fp8_f32(t4.x, t4.y, 0, false);
        tt     = __builtin_amdgcn_cvt_pk_fp8_f32(t4.z, t4.w, tt, true);
        *(int*)(ldsA + off) = pp;
        *(int*)(ldsB + off) = tt;
    }
#pragma unroll
    for (int mask = 1; mask < 16; mask <<= 1) {
        dsum += __shfl_xor(dsum, mask);
        tsum += __shfl_xor(tsum, mask);
    }
    if (c == 0) {
        const float sg = sigma[0];
        const float c2 = -0.5f * LOG2E / (sg * sg);
        diag[row] = dsum;
        t2[row]   = tsum;
        t2c2[row] = tsum * c2;
    }
    __syncthreads();

    const size_t base = (size_t)rt * 4096;
    const uint4 va = *(const uint4*)(ldsA + t * 16);
    const uint4 vb = *(const uint4*)(ldsB + t * 16);
    *(uint4*)(Ap + base + (size_t)t * 16) = va;
    *(uint4*)(Bp + base + (size_t)t * 16) = vb;
}

// ---------------------------------------------------------------------------
// Main v15 (MX-fp8): EXACT v9 geometry (session-best, R2 total 94.66:
// BM=256, mt=4, 256 thr, (256,2), 2 independent WGs/CU, one barrier/tile;
// setprio removed — R8 A/B showed neutral). ONE substantive change:
// fragment loads are now IN-PLACE half-loads through a union so the two
// ds_read_b128 / global_load_dwordx4 per fragment land directly in the
// adjacent register quads of the v8i32 MFMA operand. The previous
// (intx8){lo.x,...,hi.w} construction forced ~8 v_mov per fragment
// (~70 movs/tile/thread) — a prime suspect for R7's unexplained VALUBusy
// (21% = 11us/WG vs ~2.5us of hand-counted softmax arithmetic) sitting on
// the latency-critical path at 2 waves/SIMD.
// ---------------------------------------------------------------------------
__global__ __launch_bounds__(256, 2) void main_kernel(
        const uint8_t* __restrict__ Ap, const uint8_t* __restrict__ Bp,
        const float* __restrict__ t2c2, const float* __restrict__ sigma,
        float2* __restrict__ partials) {
    __shared__ __align__(16) uint8_t ldsB[2][BN * DIM];   // 2 x 16 KB

    const int lane   = threadIdx.x & 63;
    const int wave   = threadIdx.x >> 6;
    const int rowBlk = blockIdx.x;    // 0..31
    const int split  = blockIdx.y;    // 0..15

    const float sg = sigma[0];
    const float c1 = LOG2E / (sg * sg);     // logits(log2) = dot*c1 + t2c2
    const float floor2 = -108.0f * c1;      // overflow-safe offset floor

    // stage tile 0 first (16 KB = sixteen 1 KB chunks; 4 per wave) so it
    // overlaps the afrag global loads below.
    {
        const int j0 = split * COLS_PER_SPLIT;
        const char* gbase = (const char*)(Bp + (size_t)(j0 >> 4) * 4096);
#pragma unroll
        for (int q = 0; q < 4; ++q) {
            const int ch = wave * 4 + q;                // 0..15 x 1 KB
            __builtin_amdgcn_global_load_lds(
                (const __attribute__((address_space(1))) void*)(gbase + ch * 1024 + (size_t)lane * 16),
                (__attribute__((address_space(3))) void*)((char*)ldsB[0] + ch * 1024),
                16, 0, 0);
        }
    }

    // resident A fragments: rows rowBlk*256 + wave*64 + mt*16 + (lane&15)
    frag8 afrag[4][2];
#pragma unroll
    for (int mt = 0; mt < 4; ++mt) {
        const uint8_t* base = Ap + (size_t)(rowBlk * 16 + wave * 4 + mt) * 4096 + lane * 16;
#pragma unroll
        for (int ks = 0; ks < 2; ++ks) {
            afrag[mt][ks].v4[0] = *(const intx4*)(base + ks * 2048);
            afrag[mt][ks].v4[1] = *(const intx4*)(base + ks * 2048 + 1024);
        }
    }

    floatx2 m2[4][2], l2[4][2];
#pragma unroll
    for (int mt = 0; mt < 4; ++mt)
#pragma unroll
        for (int rp = 0; rp < 2; ++rp) {
            m2[mt][rp] = (floatx2){floor2, floor2};
            l2[mt][rp] = (floatx2){0.f, 0.f};
        }

    __syncthreads();

    for (int ct = 0; ct < NTILES; ++ct) {
        const uint8_t* cur = ldsB[ct & 1];
        const int j0 = split * COLS_PER_SPLIT + ct * BN;

        // t2c2 loads issued FIRST (consumed after the K-loop): their wait is
        // then vmcnt(4), leaving the staging loads below in flight.
        float tvc[4];
#pragma unroll
        for (int nt = 0; nt < 4; ++nt)
            tvc[nt] = t2c2[j0 + nt * 16 + (lane & 15)];

        // stage NEXT tile into the other buffer (read-complete since the
        // previous barrier); drained at this tile's end barrier.
        if (ct + 1 < NTILES) {
            const char* gbase = (const char*)(Bp + (size_t)((j0 + BN) >> 4) * 4096);
            char* lbase = (char*)ldsB[(ct + 1) & 1];
#pragma unroll
            for (int q = 0; q < 4; ++q) {
                const int ch = wave * 4 + q;
                __builtin_amdgcn_global_load_lds(
                    (const __attribute__((address_space(1))) void*)(gbase + ch * 1024 + (size_t)lane * 16),
                    (__attribute__((address_space(3))) void*)(lbase + ch * 1024),
                    16, 0, 0);
            }
        }

        floatx4 acc[4][4];
#pragma unroll
        for (int mt = 0; mt < 4; ++mt)
#pragma unroll
            for (int nt = 0; nt < 4; ++nt)
                acc[mt][nt] = (floatx4){0.f, 0.f, 0.f, 0.f};

#pragma unroll
        for (int ks = 0; ks < 2; ++ks) {
#pragma unroll
            for (int nt = 0; nt < 4; ++nt) {
                const uint8_t* bb = cur + nt * 4096 + ks * 2048 + lane * 16;
                frag8 bfrag;
                bfrag.v4[0] = *(const intx4*)(bb);
                bfrag.v4[1] = *(const intx4*)(bb + 1024);
#pragma unroll
                for (int mt = 0; mt < 4; ++mt) {
                    acc[mt][nt] = __builtin_amdgcn_mfma_scale_f32_16x16x128_f8f6f4(
                        afrag[mt][ks].v8, bfrag.v8, acc[mt][nt],
                        0, 0,          // cbsz=FP8(e4m3), blgp=FP8(e4m3)
                        0, 127,        // scale A: opsel 0, E8M0 127 = 1.0
                        0, 127);       // scale B
                }
            }
        }

        if (ct == 0) {
#pragma unroll
            for (int mt = 0; mt < 4; ++mt)
#pragma unroll
                for (int rp = 0; rp < 2; ++rp) {
                    floatx2 v[4];
#pragma unroll
                    for (int nt = 0; nt < 4; ++nt)
                        v[nt] = (floatx2){acc[mt][nt][2 * rp], acc[mt][nt][2 * rp + 1]} * c1 + tvc[nt];
                    floatx2 mm = __builtin_elementwise_max(
                        __builtin_elementwise_max(v[0], v[1]),
                        __builtin_elementwise_max(v[2], v[3]));
                    mm = __builtin_elementwise_max(mm, (floatx2){floor2, floor2});
                    m2[mt][rp] = mm;
                    floatx2 s = (floatx2){0.f, 0.f};
#pragma unroll
                    for (int nt = 0; nt < 4; ++nt) {
                        s.x += fast_exp2(v[nt].x - mm.x);
                        s.y += fast_exp2(v[nt].y - mm.y);
                    }
                    l2[mt][rp] = s;
                }
        } else {
#pragma unroll
            for (int mt = 0; mt < 4; ++mt)
#pragma unroll
                for (int rp = 0; rp < 2; ++rp) {
                    const floatx2 mm = m2[mt][rp];
                    floatx2 s = l2[mt][rp];
#pragma unroll
                    for (int nt = 0; nt < 4; ++nt) {
                        const floatx2 v = (floatx2){acc[mt][nt][2 * rp], acc[mt][nt][2 * rp + 1]} * c1
                                          + (tvc[nt] - mm);
                        s.x += fast_exp2(v.x);
                        s.y += fast_exp2(v.y);
                    }
                    l2[mt][rp] = s;
                }
        }

        __syncthreads();   // one barrier/tile: LDS-read fence + staging drain
    }

    // combine the 16 column-slot lanes per row; write per-split partials
#pragma unroll
    for (int mt = 0; mt < 4; ++mt)
#pragma unroll
        for (int rp = 0; rp < 2; ++rp)
#pragma unroll
            for (int z = 0; z < 2; ++z) {
                float m = m2[mt][rp][z];
                float l = l2[mt][rp][z];
#pragma unroll
                for (int mask = 1; mask < 16; mask <<= 1) {
                    const float mo = __shfl_xor(m, mask);
                    const float lo = __shfl_xor(l, mask);
                    const float mn = fmaxf(m, mo);
                    l = l * fast_exp2(m - mn) + lo * fast_exp2(mo - mn);
                    m = mn;
                }
                if ((lane & 15) == 0) {
                    const int r  = rp * 2 + z;
                    const int rw = rowBlk * BM + wave * 64 + mt * 16 + (lane >> 4) * 4 + r;
                    partials[(size_t)split * BATCH + rw] = make_float2(m, l);
                }
            }
}

// ---------------------------------------------------------------------------
// Finish (fused): 32 WGs; one row per thread; per-row lse combine + block
// sum; each block stores its sum then bumps a device-scope counter (with a
// release fence so the store is visible across XCDs); the LAST block
// re-runs the exact 64-lane butterfly the old finish2 used (bitwise-
// identical summation order) and writes the output. Saves one dispatch +
// its launch gap (~3us). Fence cost is negligible at 32 blocks (the R6
// 56us lesson was 512 fencing blocks).
// ---------------------------------------------------------------------------
__global__ __launch_bounds__(256) void finish_kernel(
        const float2* __restrict__ partials, const float* __restrict__ t2,
        const float* __restrict__ diag, const float* __restrict__ sigma,
        float* __restrict__ bsum, unsigned* __restrict__ cnt,
        float* __restrict__ out) {
    __shared__ float red[256];
    __shared__ bool isLast;
    const int tid = threadIdx.x;
    const int row = blockIdx.x * 256 + tid;
    const float sg = sigma[0];
    const float inv_nv = 1.0f / (sg * sg);

    float2 p[NSPLIT];
    float m = -__builtin_inff();
#pragma unroll
    for (int s = 0; s < NSPLIT; ++s) {
        p[s] = partials[(size_t)s * BATCH + row];
        m = fmaxf(m, p[s].x);
    }
    float L = 0.0f;
#pragma unroll
    for (int s = 0; s < NSPLIT; ++s)
        L += p[s].y * fast_exp2(p[s].x - m);
    const float lse_nat = LN2 * (m + __log2f(L));
    const float d = (diag[row] - 0.5f * t2[row]) * inv_nv;
    red[tid] = lse_nat - d;
    __syncthreads();
    for (int s = 128; s > 0; s >>= 1) {
        if (tid < s) red[tid] += red[tid + s];
        __syncthreads();
    }
    if (tid == 0) {
        bsum[blockIdx.x] = red[0];
        __threadfence();                       // release: flush to coherent point
        isLast = (atomicAdd(cnt, 1u) == 31u);
    }
    __syncthreads();
    if (isLast && tid < 64) {
        __threadfence();                       // acquire
        float v = (tid < 32) ? bsum[tid] : 0.0f;
#pragma unroll
        for (int mask = 32; mask > 0; mask >>= 1)
            v += __shfl_xor(v, mask);
        if (tid == 0) {
            const float nv = sg * sg;
            out[0] = 2.0f * nv * v / (float)BATCH;
        }
    }
}

extern "C" void kernel_launch(void* const* d_in, const int* in_sizes, int n_in,
                              void* d_out, int out_size, void* d_ws, size_t ws_size,
                              hipStream_t stream) {
    const float* pred   = (const float*)d_in[0];
    const float* target = (const float*)d_in[1];
    const float* sigma  = (const float*)d_in[2];
    float* out = (float*)d_out;

    char* ws = (char*)d_ws;
    uint8_t* Ap   = (uint8_t*)(ws);                                    // 2 MB
    uint8_t* Bp   = (uint8_t*)(ws + (size_t)BATCH * DIM);              // 2 MB
    float* t2     = (float*)(ws + (size_t)BATCH * DIM * 4);            // 32 KB
    float* diag   = (float*)(ws + (size_t)BATCH * DIM * 4 + BATCH * 4);
    float* t2c2   = (float*)(ws + (size_t)BATCH * DIM * 4 + BATCH * 8);
    float2* parts = (float2*)(ws + (size_t)BATCH * DIM * 4 + (size_t)BATCH * 12);
    float* bsum   = (float*)(ws + (size_t)BATCH * DIM * 4 + (size_t)BATCH * 12
                             + (size_t)NSPLIT * BATCH * 8);
    unsigned* cnt = (unsigned*)(ws + (size_t)BATCH * DIM * 4 + (size_t)BATCH * 12
                                + (size_t)NSPLIT * BATCH * 8 + 128);

    prep_kernel<<<BATCH / 16, 256, 0, stream>>>(pred, target, sigma, Ap, Bp, t2, diag, t2c2, cnt);
    main_kernel<<<dim3(BATCH / BM, NSPLIT), 256, 0, stream>>>(Ap, Bp, t2c2, sigma, parts);
    finish_kernel<<<BATCH / 256, 256, 0, stream>>>(parts, t2, diag, sigma, bsum, cnt, out);
}